// Round 11
// baseline (42.495 us; speedup 1.0000x reference)
//
#include <hip/hip_runtime.h>
#include <math.h>

#define HW 256
#define TW 64
#define TH 32
#define LW 68           // 2 halo + 64 + 2 halo (272B row stride, 16B-aligned)
#define LH 36           // 2 halo + 32 + 2 halo

// Schraudolph exp2: 2^x ~= bits(u32((x + 127 - sigma) * 2^23)), x <= 0.
// sigma = 0.0354 balances max relative error (~+-3.6%); error is strongly
// correlated across a window's taps and cancels in softmax normalization
// (R7 measured absmax identical to exact-exp version).
#define EXP2_C23 8388608.0f                 // 2^23
#define EXP2_B   1065056256.0f              // (127 - 0.0354) * 2^23

__device__ __forceinline__ int reflect_idx(int i) {
    i = (i < 0) ? -i : i;
    i = (i >= HW) ? (2 * HW - 2 - i) : i;
    return i;
}

__device__ __forceinline__ float4 max4(float4 a, float4 b) {
    float4 r; r.x = fmaxf(a.x, b.x); r.y = fmaxf(a.y, b.y);
    r.z = fmaxf(a.z, b.z); r.w = fmaxf(a.w, b.w); return r;
}
__device__ __forceinline__ float4 max34(float4 a, float4 b, float4 c) {
    float4 r; r.x = fmaxf(fmaxf(a.x, b.x), c.x); r.y = fmaxf(fmaxf(a.y, b.y), c.y);
    r.z = fmaxf(fmaxf(a.z, b.z), c.z); r.w = fmaxf(fmaxf(a.w, b.w), c.w); return r;
}
__device__ __forceinline__ float4 add4(float4 a, float4 b) {
    float4 r; r.x = a.x + b.x; r.y = a.y + b.y;
    r.z = a.z + b.z; r.w = a.w + b.w; return r;
}
__device__ __forceinline__ float4 sub4(float4 a, float4 b) {
    float4 r; r.x = a.x - b.x; r.y = a.y - b.y;
    r.z = a.z - b.z; r.w = a.w - b.w; return r;
}

__global__ __launch_bounds__(256)   // NO min-waves arg: lifts the 64-VGPR cap
void maxmedian_kernel(const float* __restrict__ x,
                      const float* __restrict__ mix,
                      const float* __restrict__ beta_raw,
                      float* __restrict__ out,
                      int C) {
    __shared__ __align__(16) float tile[LH * LW];

    const int tiles_x = HW / TW;                       // 4
    const int tiles_per_plane = tiles_x * (HW / TH);   // 32
    const int plane = blockIdx.x / tiles_per_plane;
    const int t     = blockIdx.x % tiles_per_plane;
    const int ty0 = (t / tiles_x) * TH;
    const int tx0 = (t % tiles_x) * TW;

    const float* __restrict__ xp = x + (size_t)plane * (HW * HW);
    const int tid = threadIdx.x;

    // ---- Stage (TH+4) x (TW+4) with reflect padding ----
    {
        const int c   = tid & 63;
        const int r0s = tid >> 6;             // 0..3
        const int gx  = tx0 + c;
        #pragma unroll
        for (int k = 0; k < 9; ++k) {
            const int r  = r0s + 4 * k;       // 0..35
            const int gy = reflect_idx(ty0 + r - 2);
            tile[r * LW + c + 2] = xp[gy * HW + gx];
        }
        if (tid < 144) {                      // cols {0,1,66,67} x 36 rows
            const int jj = tid & 3;
            const int j  = (jj < 2) ? jj : (64 + jj);
            const int r  = tid >> 2;
            const int gx2 = reflect_idx(tx0 + j - 2);
            const int gy2 = reflect_idx(ty0 + r - 2);
            tile[r * LW + j] = xp[gy2 * HW + gx2];
        }
    }
    __syncthreads();

    // ---- Parameters ----
    const int ch = plane % C;
    const float lam  = 1.0f / (1.0f + __expf(-mix[ch]));
    const float beta = 5.0f + 45.0f / (1.0f + __expf(-beta_raw[0]));
    const float bp     = beta * 1.44269504088896f;   // beta * log2(e) > 0
    const float inv_bp = 1.0f / bp;
    const float c04b   = 0.04f * bp;

    // ---- Each thread: 4-wide x 2-tall, both rows merged into ONE tap loop ----
    const int tx  = tid & 15;
    const int ryq = tid >> 4;        // 0..15
    const int r0  = ryq * 2;
    const float* lbase = &tile[r0 * LW + 4 * tx];

    const float4 w0a = *(const float4*)(lbase + 0 * LW);
    const float4 w0b = *(const float4*)(lbase + 0 * LW + 4);
    const float4 w1a = *(const float4*)(lbase + 1 * LW);
    const float4 w1b = *(const float4*)(lbase + 1 * LW + 4);
    const float4 w2a = *(const float4*)(lbase + 2 * LW);
    const float4 w2b = *(const float4*)(lbase + 2 * LW + 4);
    const float4 w3a = *(const float4*)(lbase + 3 * LW);
    const float4 w3b = *(const float4*)(lbase + 3 * LW + 4);
    const float4 w4a = *(const float4*)(lbase + 4 * LW);
    const float4 w4b = *(const float4*)(lbase + 4 * LW + 4);
    const float4 w5a = *(const float4*)(lbase + 5 * LW);
    const float4 w5b = *(const float4*)(lbase + 5 * LW + 4);

    // Column sums for row0 window (rows 0-4); row1 = row0 + w5 - w0.
    const float4 cs0A = add4(add4(add4(w0a, w1a), add4(w2a, w3a)), w4a);
    const float4 cs0B = add4(add4(add4(w0b, w1b), add4(w2b, w3b)), w4b);
    const float4 cs1A = add4(cs0A, sub4(w5a, w0a));
    const float4 cs1B = add4(cs0B, sub4(w5b, w0b));

    // Column maxes with shared vertical pairs.
    const float4 p12a = max4(w1a, w2a), p12b = max4(w1b, w2b);
    const float4 p34a = max4(w3a, w4a), p34b = max4(w3b, w4b);
    const float4 cm0A = max34(w0a, p12a, p34a);
    const float4 cm0B = max34(w0b, p12b, p34b);
    const float4 cm1A = max34(p12a, p34a, w5a);
    const float4 cm1B = max34(p12b, p34b, w5b);

    const float vv[6][8] = {
        {w0a.x,w0a.y,w0a.z,w0a.w, w0b.x,w0b.y,w0b.z,w0b.w},
        {w1a.x,w1a.y,w1a.z,w1a.w, w1b.x,w1b.y,w1b.z,w1b.w},
        {w2a.x,w2a.y,w2a.z,w2a.w, w2b.x,w2b.y,w2b.z,w2b.w},
        {w3a.x,w3a.y,w3a.z,w3a.w, w3b.x,w3b.y,w3b.z,w3b.w},
        {w4a.x,w4a.y,w4a.z,w4a.w, w4b.x,w4b.y,w4b.z,w4b.w},
        {w5a.x,w5a.y,w5a.z,w5a.w, w5b.x,w5b.y,w5b.z,w5b.w}};
    const float cs0[8] = {cs0A.x,cs0A.y,cs0A.z,cs0A.w, cs0B.x,cs0B.y,cs0B.z,cs0B.w};
    const float cs1[8] = {cs1A.x,cs1A.y,cs1A.z,cs1A.w, cs1B.x,cs1B.y,cs1B.z,cs1B.w};
    const float cm0[8] = {cm0A.x,cm0A.y,cm0A.z,cm0A.w, cm0B.x,cm0B.y,cm0B.z,cm0B.w};
    const float cm1[8] = {cm1A.x,cm1A.y,cm1A.z,cm1A.w, cm1B.x,cm1B.y,cm1B.z,cm1B.w};

    // Sliding horizontal sums / maxes for both rows.
    float S0[4], S1[4], m0[4], m1[4];
    {
        const float a12 = cs0[1] + cs0[2], a34 = cs0[3] + cs0[4], a56 = cs0[5] + cs0[6];
        const float au = a12 + a34, aw = a34 + a56;
        S0[0] = cs0[0] + au; S0[1] = au + cs0[5]; S0[2] = cs0[2] + aw; S0[3] = aw + cs0[7];
        const float b12 = cs1[1] + cs1[2], b34 = cs1[3] + cs1[4], b56 = cs1[5] + cs1[6];
        const float bu = b12 + b34, bw = b34 + b56;
        S1[0] = cs1[0] + bu; S1[1] = bu + cs1[5]; S1[2] = cs1[2] + bw; S1[3] = bw + cs1[7];

        const float h12 = fmaxf(cm0[1], cm0[2]);
        const float h34 = fmaxf(cm0[3], cm0[4]);
        const float h56 = fmaxf(cm0[5], cm0[6]);
        m0[0] = fmaxf(fmaxf(cm0[0], h12), h34);
        m0[1] = fmaxf(fmaxf(h12, h34), cm0[5]);
        m0[2] = fmaxf(fmaxf(cm0[2], h34), h56);
        m0[3] = fmaxf(fmaxf(h34, h56), cm0[7]);
        const float g12 = fmaxf(cm1[1], cm1[2]);
        const float g34 = fmaxf(cm1[3], cm1[4]);
        const float g56 = fmaxf(cm1[5], cm1[6]);
        m1[0] = fmaxf(fmaxf(cm1[0], g12), g34);
        m1[1] = fmaxf(fmaxf(g12, g34), cm1[5]);
        m1[2] = fmaxf(fmaxf(cm1[2], g34), g56);
        m1[3] = fmaxf(fmaxf(g34, g56), cm1[7]);
    }

    float bm0[4], bm1[4], ws0[4], wa0[4], ws1[4], wa1[4];
    #pragma unroll
    for (int p = 0; p < 4; ++p) {
        bm0[p] = S0[p] * c04b; ws0[p] = 0.0f; wa0[p] = 0.0f;
        bm1[p] = S1[p] * c04b; ws1[p] = 0.0f; wa1[p] = 0.0f;
    }

    // Merged 25-tap loop, Schraudolph exp2 (pure VALU, no trans pipe).
    #pragma unroll
    for (int k = 0; k < 5; ++k) {
        #pragma unroll
        for (int j = 0; j < 5; ++j) {
            #pragma unroll
            for (int p = 0; p < 4; ++p) {
                const float tv0 = fmaf(bp, vv[k][p + j], -bm0[p]);
                const float u0  = fmaf(-fabsf(tv0), EXP2_C23, EXP2_B);
                const float e0  = __uint_as_float(__float2uint_rz(u0));
                ws0[p] += e0;
                wa0[p] = fmaf(e0, tv0, wa0[p]);

                const float tv1 = fmaf(bp, vv[k + 1][p + j], -bm1[p]);
                const float u1  = fmaf(-fabsf(tv1), EXP2_C23, EXP2_B);
                const float e1  = __uint_as_float(__float2uint_rz(u1));
                ws1[p] += e1;
                wa1[p] = fmaf(e1, tv1, wa1[p]);
            }
        }
    }

    float* __restrict__ orow =
        out + (size_t)plane * (HW * HW) + (size_t)(ty0 + r0) * HW + (tx0 + 4 * tx);

    float o0[4], o1[4];
    #pragma unroll
    for (int p = 0; p < 4; ++p) {
        const float mean0 = S0[p] * 0.04f;
        const float med0  = fmaf(wa0[p] * __builtin_amdgcn_rcpf(ws0[p]), inv_bp, mean0);
        o0[p] = fmaf(lam, med0 - m0[p], m0[p]);
        const float mean1 = S1[p] * 0.04f;
        const float med1  = fmaf(wa1[p] * __builtin_amdgcn_rcpf(ws1[p]), inv_bp, mean1);
        o1[p] = fmaf(lam, med1 - m1[p], m1[p]);
    }
    float4 q0; q0.x = o0[0]; q0.y = o0[1]; q0.z = o0[2]; q0.w = o0[3];
    float4 q1; q1.x = o1[0]; q1.y = o1[1]; q1.z = o1[2]; q1.w = o1[3];
    *(float4*)orow = q0;
    *(float4*)(orow + HW) = q1;
}

extern "C" void kernel_launch(void* const* d_in, const int* in_sizes, int n_in,
                              void* d_out, int out_size, void* d_ws, size_t ws_size,
                              hipStream_t stream) {
    const float* x        = (const float*)d_in[0];
    const float* mix      = (const float*)d_in[1];
    const float* beta_raw = (const float*)d_in[2];
    float* out            = (float*)d_out;

    const int planes = in_sizes[0] / (HW * HW);                 // 128
    const int C      = in_sizes[1];                             // 32
    const int tiles_per_plane = (HW / TW) * (HW / TH);          // 32
    const int grid = planes * tiles_per_plane;                  // 4096

    maxmedian_kernel<<<grid, 256, 0, stream>>>(x, mix, beta_raw, out, C);
}

// Round 12
// 40.538 us; speedup vs baseline: 1.0483x; 1.0483x over previous
//
#include <hip/hip_runtime.h>
#include <math.h>

#define HW 256
#define TW 64
#define TH 16
#define LW 68           // 2 halo + 64 + 2 halo (272B row stride, 16B-aligned)
#define LH 20           // 2 halo + 16 + 2 halo

__device__ __forceinline__ int reflect_idx(int i) {
    i = (i < 0) ? -i : i;
    i = (i >= HW) ? (2 * HW - 2 - i) : i;
    return i;
}

__device__ __forceinline__ float4 max4(float4 a, float4 b) {
    float4 r; r.x = fmaxf(a.x, b.x); r.y = fmaxf(a.y, b.y);
    r.z = fmaxf(a.z, b.z); r.w = fmaxf(a.w, b.w); return r;
}
__device__ __forceinline__ float4 add4(float4 a, float4 b) {
    float4 r; r.x = a.x + b.x; r.y = a.y + b.y;
    r.z = a.z + b.z; r.w = a.w + b.w; return r;
}

__global__ __launch_bounds__(256)
void maxmedian_kernel(const float* __restrict__ x,
                      const float* __restrict__ mix,
                      const float* __restrict__ beta_raw,
                      float* __restrict__ out,
                      int C) {
    __shared__ __align__(16) float tile[LH * LW];

    const int tiles_x = HW / TW;                       // 4
    const int tiles_per_plane = tiles_x * (HW / TH);   // 64
    const int plane = blockIdx.x / tiles_per_plane;
    const int t     = blockIdx.x % tiles_per_plane;
    const int ty0 = (t / tiles_x) * TH;
    const int tx0 = (t % tiles_x) * TW;

    const float* __restrict__ xp = x + (size_t)plane * (HW * HW);
    const int tid = threadIdx.x;

    // ---- Stage (TH+4) x (TW+4) with reflect padding ----
    {
        const int c   = tid & 63;
        const int r0s = tid >> 6;             // 0..3
        const int gx  = tx0 + c;
        #pragma unroll
        for (int k = 0; k < 5; ++k) {
            const int r  = r0s + 4 * k;       // 0..19
            const int gy = reflect_idx(ty0 + r - 2);
            tile[r * LW + c + 2] = xp[gy * HW + gx];
        }
        if (tid < 80) {                       // cols {0,1,66,67} x 20 rows
            const int jj = tid & 3;
            const int j  = (jj < 2) ? jj : (64 + jj);
            const int r  = tid >> 2;          // 0..19
            const int gx2 = reflect_idx(tx0 + j - 2);
            const int gy2 = reflect_idx(ty0 + r - 2);
            tile[r * LW + j] = xp[gy2 * HW + gx2];
        }
    }
    __syncthreads();

    // ---- Parameters (wave-uniform -> SGPRs) ----
    const int ch = plane % C;
    const float lam  = 1.0f / (1.0f + __expf(-mix[ch]));
    const float beta = 5.0f + 45.0f / (1.0f + __expf(-beta_raw[0]));
    const float bp     = beta * 1.44269504088896f;   // beta * log2(e) > 0
    const float inv_bp = 1.0f / bp;
    const float c04b   = 0.04f * bp;

    // ---- Each thread: ONE 4-wide pixel group (row ry, cols 4*tx..4*tx+3) ----
    const int tx = tid & 15;         // 16 column groups
    const int ry = tid >> 4;         // 0..15 output rows
    const float* lbase = &tile[ry * LW + 4 * tx];

    // ---- Pass A: column sums/maxes, folding loads immediately (low live state)
    float4 csA, csB, cmA, cmB;
    {
        float4 a = *(const float4*)(lbase + 0 * LW);
        float4 b = *(const float4*)(lbase + 0 * LW + 4);
        csA = a; cmA = a; csB = b; cmB = b;
        #pragma unroll
        for (int k = 1; k < 5; ++k) {
            const float4 a2 = *(const float4*)(lbase + k * LW);
            const float4 b2 = *(const float4*)(lbase + k * LW + 4);
            csA = add4(csA, a2); cmA = max4(cmA, a2);
            csB = add4(csB, b2); cmB = max4(cmB, b2);
        }
    }

    float S[4], m[4], bm[4];
    {
        const float cs[8] = {csA.x,csA.y,csA.z,csA.w, csB.x,csB.y,csB.z,csB.w};
        const float cm[8] = {cmA.x,cmA.y,cmA.z,cmA.w, cmB.x,cmB.y,cmB.z,cmB.w};
        const float t12 = cs[1] + cs[2];
        const float t34 = cs[3] + cs[4];
        const float t56 = cs[5] + cs[6];
        const float u   = t12 + t34;
        const float w_  = t34 + t56;
        S[0] = cs[0] + u; S[1] = u + cs[5]; S[2] = cs[2] + w_; S[3] = w_ + cs[7];

        const float h12 = fmaxf(cm[1], cm[2]);
        const float h34 = fmaxf(cm[3], cm[4]);
        const float h56 = fmaxf(cm[5], cm[6]);
        m[0] = fmaxf(fmaxf(cm[0], h12), h34);
        m[1] = fmaxf(fmaxf(h12, h34), cm[5]);
        m[2] = fmaxf(fmaxf(cm[2], h34), h56);
        m[3] = fmaxf(fmaxf(h34, h56), cm[7]);

        #pragma unroll
        for (int p = 0; p < 4; ++p) bm[p] = S[p] * c04b;
    }

    // Force the window out of registers: pass B re-reads LDS row by row.
    asm volatile("" ::: "memory");

    // ---- Pass B: 25 taps, window rows re-read from LDS (8 floats live) ----
    float ws[4] = {0.f, 0.f, 0.f, 0.f};
    float wa[4] = {0.f, 0.f, 0.f, 0.f};
    #pragma unroll
    for (int k = 0; k < 5; ++k) {
        const float4 a = *(const float4*)(lbase + k * LW);
        const float4 b = *(const float4*)(lbase + k * LW + 4);
        const float v[8] = {a.x,a.y,a.z,a.w, b.x,b.y,b.z,b.w};
        #pragma unroll
        for (int j = 0; j < 5; ++j) {
            #pragma unroll
            for (int p = 0; p < 4; ++p) {
                const float tv = fmaf(bp, v[p + j], -bm[p]);     // beta'*(v-mean)
                const float e  = __builtin_amdgcn_exp2f(-fabsf(tv));
                ws[p] += e;
                wa[p] = fmaf(e, tv, wa[p]);
            }
        }
        asm volatile("" ::: "memory");   // drop this row; re-read next from LDS
    }

    float o[4];
    #pragma unroll
    for (int p = 0; p < 4; ++p) {
        const float mean = S[p] * 0.04f;
        const float med  = fmaf(wa[p] * __builtin_amdgcn_rcpf(ws[p]), inv_bp, mean);
        o[p] = fmaf(lam, med - m[p], m[p]);
    }
    float4 o4; o4.x = o[0]; o4.y = o[1]; o4.z = o[2]; o4.w = o[3];

    float* __restrict__ orow =
        out + (size_t)plane * (HW * HW) + (size_t)(ty0 + ry) * HW + (tx0 + 4 * tx);
    *(float4*)orow = o4;
}

extern "C" void kernel_launch(void* const* d_in, const int* in_sizes, int n_in,
                              void* d_out, int out_size, void* d_ws, size_t ws_size,
                              hipStream_t stream) {
    const float* x        = (const float*)d_in[0];
    const float* mix      = (const float*)d_in[1];
    const float* beta_raw = (const float*)d_in[2];
    float* out            = (float*)d_out;

    const int planes = in_sizes[0] / (HW * HW);                 // 128
    const int C      = in_sizes[1];                             // 32
    const int tiles_per_plane = (HW / TW) * (HW / TH);          // 64
    const int grid = planes * tiles_per_plane;                  // 8192

    maxmedian_kernel<<<grid, 256, 0, stream>>>(x, mix, beta_raw, out, C);
}

// Round 13
// 39.327 us; speedup vs baseline: 1.0806x; 1.0308x over previous
//
#include <hip/hip_runtime.h>
#include <math.h>

#define HW 256
#define TW 64
#define TH 32
#define LW 68           // 2 halo + 64 + 2 halo (272B row stride, 16B-aligned)
#define LH 36           // 2 halo + 32 + 2 halo

typedef float f32x2 __attribute__((ext_vector_type(2)));

__device__ __forceinline__ int reflect_idx(int i) {
    i = (i < 0) ? -i : i;
    i = (i >= HW) ? (2 * HW - 2 - i) : i;
    return i;
}

__device__ __forceinline__ float4 max4(float4 a, float4 b) {
    float4 r; r.x = fmaxf(a.x, b.x); r.y = fmaxf(a.y, b.y);
    r.z = fmaxf(a.z, b.z); r.w = fmaxf(a.w, b.w); return r;
}
__device__ __forceinline__ float4 max34(float4 a, float4 b, float4 c) {
    float4 r; r.x = fmaxf(fmaxf(a.x, b.x), c.x); r.y = fmaxf(fmaxf(a.y, b.y), c.y);
    r.z = fmaxf(fmaxf(a.z, b.z), c.z); r.w = fmaxf(fmaxf(a.w, b.w), c.w); return r;
}
__device__ __forceinline__ float4 add4(float4 a, float4 b) {
    float4 r; r.x = a.x + b.x; r.y = a.y + b.y;
    r.z = a.z + b.z; r.w = a.w + b.w; return r;
}
__device__ __forceinline__ float4 sub4(float4 a, float4 b) {
    float4 r; r.x = a.x - b.x; r.y = a.y - b.y;
    r.z = a.z - b.z; r.w = a.w - b.w; return r;
}

// One output row, 4 pixels, tap loop packed as f32x2 pairs (v_pk_fma/v_pk_add).
__device__ __forceinline__ void proc_row(
    float4 A0, float4 B0, float4 A1, float4 B1, float4 A2, float4 B2,
    float4 A3, float4 B3, float4 A4, float4 B4,
    float4 cmA, float4 cmB, float4 csA, float4 csB,
    float bp, float c04b, float inv_bp, float lam,
    float* __restrict__ orow)
{
    const float cs[8] = {csA.x,csA.y,csA.z,csA.w, csB.x,csB.y,csB.z,csB.w};
    const float cm[8] = {cmA.x,cmA.y,cmA.z,cmA.w, cmB.x,cmB.y,cmB.z,cmB.w};
    const float vv[5][8] = {
        {A0.x,A0.y,A0.z,A0.w, B0.x,B0.y,B0.z,B0.w},
        {A1.x,A1.y,A1.z,A1.w, B1.x,B1.y,B1.z,B1.w},
        {A2.x,A2.y,A2.z,A2.w, B2.x,B2.y,B2.z,B2.w},
        {A3.x,A3.y,A3.z,A3.w, B3.x,B3.y,B3.z,B3.w},
        {A4.x,A4.y,A4.z,A4.w, B4.x,B4.y,B4.z,B4.w}};

    // Sliding horizontal sums of the 8 column sums (5-wide windows)
    const float t12 = cs[1] + cs[2];
    const float t34 = cs[3] + cs[4];
    const float t56 = cs[5] + cs[6];
    const float u   = t12 + t34;
    const float w_  = t34 + t56;
    const float S[4] = {cs[0] + u, u + cs[5], cs[2] + w_, w_ + cs[7]};

    // Horizontal max of 5 column-maxes with shared pairs (v_max3 fusion)
    const float h12 = fmaxf(cm[1], cm[2]);
    const float h34 = fmaxf(cm[3], cm[4]);
    const float h56 = fmaxf(cm[5], cm[6]);
    const float m[4] = {fmaxf(fmaxf(cm[0], h12), h34),
                        fmaxf(fmaxf(h12, h34), cm[5]),
                        fmaxf(fmaxf(cm[2], h34), h56),
                        fmaxf(fmaxf(h34, h56), cm[7])};

    const f32x2 bp2   = {bp, bp};
    const f32x2 nbm01 = {-(S[0] * c04b), -(S[1] * c04b)};
    const f32x2 nbm23 = {-(S[2] * c04b), -(S[3] * c04b)};
    f32x2 ws01 = {0.0f, 0.0f}, ws23 = {0.0f, 0.0f};
    f32x2 wa01 = {0.0f, 0.0f}, wa23 = {0.0f, 0.0f};

    #pragma unroll
    for (int k = 0; k < 5; ++k) {
        #pragma unroll
        for (int j = 0; j < 5; ++j) {
            const f32x2 v01 = {vv[k][j],     vv[k][j + 1]};
            const f32x2 v23 = {vv[k][j + 2], vv[k][j + 3]};
            const f32x2 tv01 = __builtin_elementwise_fma(bp2, v01, nbm01);
            const f32x2 tv23 = __builtin_elementwise_fma(bp2, v23, nbm23);
            f32x2 e01, e23;
            e01.x = __builtin_amdgcn_exp2f(-fabsf(tv01.x));
            e01.y = __builtin_amdgcn_exp2f(-fabsf(tv01.y));
            e23.x = __builtin_amdgcn_exp2f(-fabsf(tv23.x));
            e23.y = __builtin_amdgcn_exp2f(-fabsf(tv23.y));
            ws01 += e01;                                        // v_pk_add_f32
            ws23 += e23;
            wa01 = __builtin_elementwise_fma(e01, tv01, wa01);  // v_pk_fma_f32
            wa23 = __builtin_elementwise_fma(e23, tv23, wa23);
        }
    }

    const float ws[4] = {ws01.x, ws01.y, ws23.x, ws23.y};
    const float wa[4] = {wa01.x, wa01.y, wa23.x, wa23.y};

    float o[4];
    #pragma unroll
    for (int p = 0; p < 4; ++p) {
        const float mean = S[p] * 0.04f;
        const float med  = fmaf(wa[p] * __builtin_amdgcn_rcpf(ws[p]), inv_bp, mean);
        o[p] = fmaf(lam, med - m[p], m[p]);
    }
    float4 o4; o4.x = o[0]; o4.y = o[1]; o4.z = o[2]; o4.w = o[3];
    *(float4*)orow = o4;
}

__global__ __launch_bounds__(256, 4)
void maxmedian_kernel(const float* __restrict__ x,
                      const float* __restrict__ mix,
                      const float* __restrict__ beta_raw,
                      float* __restrict__ out,
                      int C) {
    __shared__ __align__(16) float tile[LH * LW];

    const int tiles_x = HW / TW;                       // 4
    const int tiles_per_plane = tiles_x * (HW / TH);   // 32
    const int plane = blockIdx.x / tiles_per_plane;
    const int t     = blockIdx.x % tiles_per_plane;
    const int ty0 = (t / tiles_x) * TH;
    const int tx0 = (t % tiles_x) * TW;

    const float* __restrict__ xp = x + (size_t)plane * (HW * HW);
    const int tid = threadIdx.x;

    // ---- Stage (TH+4) x (TW+4) with reflect padding ----
    {
        const int c   = tid & 63;
        const int r0s = tid >> 6;             // 0..3
        const int gx  = tx0 + c;
        #pragma unroll
        for (int k = 0; k < 9; ++k) {
            const int r  = r0s + 4 * k;       // 0..35
            const int gy = reflect_idx(ty0 + r - 2);
            tile[r * LW + c + 2] = xp[gy * HW + gx];
        }
        if (tid < 144) {                      // cols {0,1,66,67} x 36 rows
            const int jj = tid & 3;
            const int j  = (jj < 2) ? jj : (64 + jj);
            const int r  = tid >> 2;
            const int gx2 = reflect_idx(tx0 + j - 2);
            const int gy2 = reflect_idx(ty0 + r - 2);
            tile[r * LW + j] = xp[gy2 * HW + gx2];
        }
    }
    __syncthreads();

    // ---- Parameters ----
    const int ch = plane % C;
    const float lam  = 1.0f / (1.0f + __expf(-mix[ch]));
    const float beta = 5.0f + 45.0f / (1.0f + __expf(-beta_raw[0]));
    const float bp     = beta * 1.44269504088896f;   // beta * log2(e) > 0
    const float inv_bp = 1.0f / bp;
    const float c04b   = 0.04f * bp;

    // ---- Each thread: 4-wide x 2-tall ----
    const int tx  = tid & 15;
    const int ryq = tid >> 4;        // 0..15
    const int r0  = ryq * 2;
    const float* lbase = &tile[r0 * LW + 4 * tx];

    float4 w0a = *(const float4*)(lbase + 0 * LW);
    float4 w0b = *(const float4*)(lbase + 0 * LW + 4);
    float4 w1a = *(const float4*)(lbase + 1 * LW);
    float4 w1b = *(const float4*)(lbase + 1 * LW + 4);
    float4 w2a = *(const float4*)(lbase + 2 * LW);
    float4 w2b = *(const float4*)(lbase + 2 * LW + 4);
    float4 w3a = *(const float4*)(lbase + 3 * LW);
    float4 w3b = *(const float4*)(lbase + 3 * LW + 4);
    float4 w4a = *(const float4*)(lbase + 4 * LW);
    float4 w4b = *(const float4*)(lbase + 4 * LW + 4);
    float4 w5a = *(const float4*)(lbase + 5 * LW);
    float4 w5b = *(const float4*)(lbase + 5 * LW + 4);

    float4 csA = add4(add4(add4(w0a, w1a), add4(w2a, w3a)), w4a);
    float4 csB = add4(add4(add4(w0b, w1b), add4(w2b, w3b)), w4b);

    const float4 p12a = max4(w1a, w2a), p12b = max4(w1b, w2b);
    const float4 p34a = max4(w3a, w4a), p34b = max4(w3b, w4b);
    const float4 cm0a = max34(w0a, p12a, p34a);
    const float4 cm0b = max34(w0b, p12b, p34b);

    float* __restrict__ orow =
        out + (size_t)plane * (HW * HW) + (size_t)(ty0 + r0) * HW + (tx0 + 4 * tx);

    proc_row(w0a,w0b, w1a,w1b, w2a,w2b, w3a,w3b, w4a,w4b,
             cm0a, cm0b, csA, csB, bp, c04b, inv_bp, lam, orow);

    csA = add4(csA, sub4(w5a, w0a));
    csB = add4(csB, sub4(w5b, w0b));
    const float4 cm1a = max34(p12a, p34a, w5a);
    const float4 cm1b = max34(p12b, p34b, w5b);

    proc_row(w1a,w1b, w2a,w2b, w3a,w3b, w4a,w4b, w5a,w5b,
             cm1a, cm1b, csA, csB, bp, c04b, inv_bp, lam, orow + HW);
}

extern "C" void kernel_launch(void* const* d_in, const int* in_sizes, int n_in,
                              void* d_out, int out_size, void* d_ws, size_t ws_size,
                              hipStream_t stream) {
    const float* x        = (const float*)d_in[0];
    const float* mix      = (const float*)d_in[1];
    const float* beta_raw = (const float*)d_in[2];
    float* out            = (float*)d_out;

    const int planes = in_sizes[0] / (HW * HW);                 // 128
    const int C      = in_sizes[1];                             // 32
    const int tiles_per_plane = (HW / TW) * (HW / TH);          // 32
    const int grid = planes * tiles_per_plane;                  // 4096

    maxmedian_kernel<<<grid, 256, 0, stream>>>(x, mix, beta_raw, out, C);
}